// Round 3
// baseline (553.843 us; speedup 1.0000x reference)
//
#include <hip/hip_runtime.h>
#include <cstdint>
#include <cstddef>

// ====================================================================
// Attention block: out = softmax(mask? NEG : (QK^T*scale + bias)) V @ Wout^T
// B=8 L=1024 E=1024 H=16 A=64.
// float inputs -> const float*, bool mask -> const int*, output -> float*.
// Compute in bf16 MFMA. Workspace: Q,K,Vt,Vals bf16 = 67 MiB.
// k_attn: swapped QK^T (S^T layout) so bias/mask are float4/int4 loads;
// no block barriers (per-wave LDS P buffer, parity double-buffered).
// ====================================================================

typedef __bf16 bf16;
typedef __attribute__((ext_vector_type(8))) __bf16 bf16x8;
typedef __attribute__((ext_vector_type(4))) __bf16 bf16x4;
typedef __attribute__((ext_vector_type(4))) float f32x4;
typedef __attribute__((ext_vector_type(4))) int i32x4;

#define MFMA_BF16(a, b, c) __builtin_amdgcn_mfma_f32_16x16x32_bf16(a, b, c, 0, 0, 0)

static constexpr float SCALE_ = 0.125f;                     // 64^-0.5
static constexpr float NEGF  = -3.4028234663852886e38f;     // finfo(f32).min (finite!)

__device__ __forceinline__ void gload_lds16(const bf16* g, bf16* l) {
  __builtin_amdgcn_global_load_lds((const __attribute__((address_space(1))) void*)g,
                                   (__attribute__((address_space(3))) void*)l,
                                   16, 0, 0);
}

__device__ __forceinline__ bf16x8 cvt8(const float* p) {
  f32x4 a = *(const f32x4*)p;
  f32x4 b = *(const f32x4*)(p + 4);
  bf16x8 r = {(bf16)a[0], (bf16)a[1], (bf16)a[2], (bf16)a[3],
              (bf16)b[0], (bf16)b[1], (bf16)b[2], (bf16)b[3]};
  return r;
}

// --------------------------------------------------------------------
// Kernel 1: QKV projection.  C[8192,3072] = X[8192,1024] @ W[3072,1024]^T
// f32 inputs staged to LDS as bf16. Epilogue scatters into Q[B,H,L,A],
// K[B,H,L,A], Vt[B,H,A,L] (bf16). col n: h=n/192, r=n%192 (Q/K/V split).
// --------------------------------------------------------------------
__global__ __launch_bounds__(256) void k_qkv(const float* __restrict__ X,
                                             const float* __restrict__ W,
                                             bf16* __restrict__ Q,
                                             bf16* __restrict__ Kc,
                                             bf16* __restrict__ Vt) {
  constexpr int K = 1024;
  __shared__ __align__(16) bf16 As[128 * 64];
  __shared__ __align__(16) bf16 Bs[128 * 64];
  const int t = threadIdx.x;
  const int lane = t & 63, w = t >> 6;
  const int wr = w >> 1, wc = w & 1;
  const int li = lane & 15, g = lane >> 4;
  const int m0 = (blockIdx.x & 63) * 128;   // 64 m-tiles
  const int n0 = (blockIdx.x >> 6) * 128;   // 24 n-tiles

  f32x4 acc[4][4] = {};

  for (int kt = 0; kt < K; kt += 64) {
#pragma unroll
    for (int it = 0; it < 4; ++it) {
      int c = it * 256 + t;               // 0..1023, 8 bf16 elems each
      int row = c >> 3, col = (c & 7) << 3;
      *(bf16x8*)(As + c * 8) = cvt8(X + (size_t)(m0 + row) * K + kt + col);
      *(bf16x8*)(Bs + c * 8) = cvt8(W + (size_t)(n0 + row) * K + kt + col);
    }
    __syncthreads();
#pragma unroll
    for (int kk = 0; kk < 2; ++kk) {
      bf16x8 af[4], bfr[4];
#pragma unroll
      for (int i = 0; i < 4; ++i)
        af[i] = *(const bf16x8*)(As + (wr * 64 + i * 16 + li) * 64 + kk * 32 + g * 8);
#pragma unroll
      for (int j = 0; j < 4; ++j)
        bfr[j] = *(const bf16x8*)(Bs + (wc * 64 + j * 16 + li) * 64 + kk * 32 + g * 8);
#pragma unroll
      for (int i = 0; i < 4; ++i)
#pragma unroll
        for (int j = 0; j < 4; ++j)
          acc[i][j] = MFMA_BF16(af[i], bfr[j], acc[i][j]);
    }
    __syncthreads();
  }

#pragma unroll
  for (int i = 0; i < 4; ++i) {
#pragma unroll
    for (int j = 0; j < 4; ++j) {
      int col = n0 + wc * 64 + j * 16 + li;
      int h = col / 192, r = col % 192;
#pragma unroll
      for (int rg = 0; rg < 4; ++rg) {
        int row = m0 + wr * 64 + i * 16 + g * 4 + rg;
        int b = row >> 10, l = row & 1023;
        bf16 v = (bf16)acc[i][j][rg];
        if (r < 64)
          Q[((size_t)((b * 16 + h) * 1024 + l)) * 64 + r] = v;
        else if (r < 128)
          Kc[((size_t)((b * 16 + h) * 1024 + l)) * 64 + (r - 64)] = v;
        else
          Vt[((size_t)((b * 16 + h) * 64 + (r - 128))) * 1024 + l] = v;
      }
    }
  }
}

// --------------------------------------------------------------------
// Kernel 2: flash attention. Grid 2048 x 256 threads; bh = lid%128 so all
// 16 q-tiles of one head land on the same XCD (K/V L2-resident).
// Per wave: 16 q rows (q = q0 + (lane&15)). Swapped QK^T -> S^T:
//   s[kkf][rg] = S[q = q0+li][k = kkt + kkf*16 + g*4 + rg]
// so bias is a float4 load, mask an int4 load, and softmax state is one
// scalar (m,l) per lane. No block barriers: P goes through a per-wave
// parity-double-buffered LDS slice with in-wave lgkmcnt ordering.
// --------------------------------------------------------------------
__global__ __launch_bounds__(256) void k_attn(const bf16* __restrict__ Q,
                                              const bf16* __restrict__ Kc,
                                              const bf16* __restrict__ Vt,
                                              const float* __restrict__ bias,
                                              const int* __restrict__ mask,
                                              bf16* __restrict__ Vals) {
  __shared__ __align__(16) bf16 Plds[4][2][16][80];  // per-wave, 16B-aligned rows
  const int t = threadIdx.x, lane = t & 63, w = t >> 6;
  const int li = lane & 15, g = lane >> 4;
  const int lid = blockIdx.x;
  const int bh = lid & 127;            // b*16+h; lid%8 == bh%8 -> same XCD
  const int qt = lid >> 7;
  const int b = bh >> 4, h = bh & 15;
  const int q0 = qt * 64 + w * 16;     // wave's 16 q rows

  const bf16* Qbase = Q + ((size_t)bh << 10) * 64;
  const bf16* Kbase = Kc + ((size_t)bh << 10) * 64;
  const bf16* Vbase = Vt + ((size_t)bh << 6) * 1024;
  const float* brow = bias + ((size_t)bh << 20) + (size_t)(q0 + li) * 1024 + g * 4;
  const int*   mrow = mask + ((size_t)bh << 20) + (size_t)(q0 + li) * 1024 + g * 4;

  bf16x8 qf[2];
#pragma unroll
  for (int c = 0; c < 2; ++c)
    qf[c] = *(const bf16x8*)(Qbase + (size_t)(q0 + li) * 64 + c * 32 + g * 8);

  f32x4 oacc[4] = {};
  float mrun = NEGF;
  float lrun = 0.f;

  for (int kt6 = 0; kt6 < 16; ++kt6) {
    const int kkt = kt6 * 64;
    const int par = kt6 & 1;

    // ---- bias/mask vector loads (issued first, consumed mid-tile) ----
    f32x4 b4[4];
    i32x4 m4[4];
#pragma unroll
    for (int kkf = 0; kkf < 4; ++kkf) {
      b4[kkf] = *(const f32x4*)(brow + kkt + kkf * 16);
      m4[kkf] = *(const i32x4*)(mrow + kkt + kkf * 16);
    }

    // ---- S^T = K Q^T (per wave: 64k x 16q as 4 fragments) ----
    f32x4 s[4];
#pragma unroll
    for (int kkf = 0; kkf < 4; ++kkf) {
      f32x4 ss = {0.f, 0.f, 0.f, 0.f};
#pragma unroll
      for (int c = 0; c < 2; ++c) {
        bf16x8 kf = *(const bf16x8*)(Kbase + (size_t)(kkt + kkf * 16 + li) * 64 + c * 32 + g * 8);
        ss = MFMA_BF16(kf, qf[c], ss);
      }
      s[kkf] = ss;
    }

    // ---- scale + bias + mask, tile max ----
    float tmax = NEGF;
#pragma unroll
    for (int kkf = 0; kkf < 4; ++kkf) {
#pragma unroll
      for (int rg = 0; rg < 4; ++rg) {
        float sv = s[kkf][rg] * SCALE_ + b4[kkf][rg];
        sv = m4[kkf][rg] ? NEGF : sv;
        s[kkf][rg] = sv;
        tmax = fmaxf(tmax, sv);
      }
    }
    tmax = fmaxf(tmax, __shfl_xor(tmax, 16));
    tmax = fmaxf(tmax, __shfl_xor(tmax, 32));

    float mnew = fmaxf(mrun, tmax);
    float corr = __expf(mrun - mnew);   // NEG-NEG=0 -> 1; NEG-real -> 0
    float psum = 0.f;

    // ---- P = exp(s - m): pack 4 consecutive k to bf16x4, one b64 write ----
#pragma unroll
    for (int kkf = 0; kkf < 4; ++kkf) {
      float p0 = __expf(s[kkf][0] - mnew);
      float p1 = __expf(s[kkf][1] - mnew);
      float p2 = __expf(s[kkf][2] - mnew);
      float p3 = __expf(s[kkf][3] - mnew);
      psum += (p0 + p1) + (p2 + p3);
      bf16x4 pk = {(bf16)p0, (bf16)p1, (bf16)p2, (bf16)p3};
      *(bf16x4*)(&Plds[w][par][li][kkf * 16 + g * 4]) = pk;
    }
    psum += __shfl_xor(psum, 16);
    psum += __shfl_xor(psum, 32);
    lrun = lrun * corr + psum;
    mrun = mnew;

    // ---- rescale O by corr of the row each accumulator reg belongs to ----
    float cq[4];
#pragma unroll
    for (int rg = 0; rg < 4; ++rg) cq[rg] = __shfl(corr, g * 4 + rg);
#pragma unroll
    for (int af = 0; af < 4; ++af)
#pragma unroll
      for (int rg = 0; rg < 4; ++rg) oacc[af][rg] *= cq[rg];

    // ---- in-wave ordering: P writes visible before P reads ----
    asm volatile("s_waitcnt lgkmcnt(0)" ::: "memory");
    __builtin_amdgcn_sched_barrier(0);

    // ---- O += P V ----
#pragma unroll
    for (int c = 0; c < 2; ++c) {
      bf16x8 pf = *(const bf16x8*)(&Plds[w][par][li][c * 32 + g * 8]);
#pragma unroll
      for (int af = 0; af < 4; ++af) {
        bf16x8 vf = *(const bf16x8*)(Vbase + (size_t)(af * 16 + li) * 1024 + kkt + c * 32 + g * 8);
        oacc[af] = MFMA_BF16(pf, vf, oacc[af]);
      }
    }
  }

  float linv[4];
#pragma unroll
  for (int rg = 0; rg < 4; ++rg) linv[rg] = 1.0f / __shfl(lrun, g * 4 + rg);
#pragma unroll
  for (int af = 0; af < 4; ++af) {
#pragma unroll
    for (int rg = 0; rg < 4; ++rg) {
      int q = q0 + g * 4 + rg;
      int col = h * 64 + af * 16 + li;
      Vals[(((size_t)(b * 1024 + q)) << 10) + col] = (bf16)(oacc[af][rg] * linv[rg]);
    }
  }
}

// --------------------------------------------------------------------
// Kernel 3: output projection. out[8192,1024] = Vals @ Wout[1024,1024]^T
// A (Vals) is bf16 -> global_load_lds; B (Wout) is f32 -> reg-stage+cvt.
// Output f32.
// --------------------------------------------------------------------
__global__ __launch_bounds__(256) void k_out(const bf16* __restrict__ X,
                                             const float* __restrict__ W,
                                             float* __restrict__ Out) {
  constexpr int K = 1024;
  __shared__ __align__(16) bf16 As[128 * 64];
  __shared__ __align__(16) bf16 Bs[128 * 64];
  const int t = threadIdx.x;
  const int lane = t & 63, w = t >> 6;
  const int wr = w >> 1, wc = w & 1;
  const int li = lane & 15, g = lane >> 4;
  const int m0 = (blockIdx.x & 63) * 128;   // 64 m-tiles
  const int n0 = (blockIdx.x >> 6) * 128;   // 8 n-tiles

  f32x4 acc[4][4] = {};

  for (int kt = 0; kt < K; kt += 64) {
#pragma unroll
    for (int it = 0; it < 4; ++it) {
      int c = it * 256 + t;
      int row = c >> 3, col = (c & 7) << 3;
      gload_lds16(X + (size_t)(m0 + row) * K + kt + col, As + c * 8);
      *(bf16x8*)(Bs + c * 8) = cvt8(W + (size_t)(n0 + row) * K + kt + col);
    }
    __syncthreads();
#pragma unroll
    for (int kk = 0; kk < 2; ++kk) {
      bf16x8 af[4], bfr[4];
#pragma unroll
      for (int i = 0; i < 4; ++i)
        af[i] = *(const bf16x8*)(As + (wr * 64 + i * 16 + li) * 64 + kk * 32 + g * 8);
#pragma unroll
      for (int j = 0; j < 4; ++j)
        bfr[j] = *(const bf16x8*)(Bs + (wc * 64 + j * 16 + li) * 64 + kk * 32 + g * 8);
#pragma unroll
      for (int i = 0; i < 4; ++i)
#pragma unroll
        for (int j = 0; j < 4; ++j)
          acc[i][j] = MFMA_BF16(af[i], bfr[j], acc[i][j]);
    }
    __syncthreads();
  }

#pragma unroll
  for (int i = 0; i < 4; ++i) {
#pragma unroll
    for (int j = 0; j < 4; ++j) {
      int col = n0 + wc * 64 + j * 16 + li;
#pragma unroll
      for (int rg = 0; rg < 4; ++rg) {
        int row = m0 + wr * 64 + i * 16 + g * 4 + rg;
        Out[((size_t)row << 10) + col] = acc[i][j][rg];
      }
    }
  }
}

// --------------------------------------------------------------------
extern "C" void kernel_launch(void* const* d_in, const int* in_sizes, int n_in,
                              void* d_out, int out_size, void* d_ws, size_t ws_size,
                              hipStream_t stream) {
  const float* emb  = (const float*)d_in[0];
  const int*   mask = (const int*)d_in[1];
  const float* bias = (const float*)d_in[2];
  const float* Wqkv = (const float*)d_in[3];
  const float* Wout = (const float*)d_in[4];
  float* out = (float*)d_out;

  const size_t HEADS_ELEMS = (size_t)8 * 16 * 1024 * 64;  // 8.39M elems
  bf16* Q    = (bf16*)d_ws;
  bf16* Kc   = Q + HEADS_ELEMS;
  bf16* Vt   = Kc + HEADS_ELEMS;
  bf16* Vals = Vt + HEADS_ELEMS;   // total ~67 MiB of ws

  k_qkv<<<dim3(64 * 24), 256, 0, stream>>>(emb, Wqkv, Q, Kc, Vt);
  k_attn<<<dim3(2048), 256, 0, stream>>>(Q, Kc, Vt, bias, mask, Vals);
  k_out<<<dim3(64 * 8), 256, 0, stream>>>(Vals, Wout, out);
}

// Round 4
// 528.978 us; speedup vs baseline: 1.0470x; 1.0470x over previous
//
#include <hip/hip_runtime.h>
#include <cstdint>
#include <cstddef>

// ====================================================================
// Attention block: out = softmax(mask? NEG : (QK^T*scale + bias)) V @ Wout^T
// B=8 L=1024 E=1024 H=16 A=64.
// float inputs -> const float*, bool mask -> const int*, output -> float*.
// Compute in bf16 MFMA. Workspace: Q,K,Vt,Vals bf16 = 67 MiB.
// k_attn: swapped QK^T (S^T layout), float4/int4 bias/mask PREFETCHED one
// tile ahead, mask folded into bias early; P transpose via per-wave
// parity-double-buffered LDS (pad-72 rows, b32 writes) with NO barriers
// and NO scheduling walls (compiler-ordered DS dependencies).
// ====================================================================

typedef __bf16 bf16;
typedef __attribute__((ext_vector_type(8))) __bf16 bf16x8;
typedef __attribute__((ext_vector_type(2))) __bf16 bf16x2;
typedef __attribute__((ext_vector_type(4))) float f32x4;
typedef __attribute__((ext_vector_type(4))) int i32x4;

#define MFMA_BF16(a, b, c) __builtin_amdgcn_mfma_f32_16x16x32_bf16(a, b, c, 0, 0, 0)

static constexpr float SCALE_ = 0.125f;                     // 64^-0.5
static constexpr float NEGF  = -3.4028234663852886e38f;     // finfo(f32).min (finite!)

__device__ __forceinline__ void gload_lds16(const bf16* g, bf16* l) {
  __builtin_amdgcn_global_load_lds((const __attribute__((address_space(1))) void*)g,
                                   (__attribute__((address_space(3))) void*)l,
                                   16, 0, 0);
}

__device__ __forceinline__ bf16x8 cvt8(const float* p) {
  f32x4 a = *(const f32x4*)p;
  f32x4 b = *(const f32x4*)(p + 4);
  bf16x8 r = {(bf16)a[0], (bf16)a[1], (bf16)a[2], (bf16)a[3],
              (bf16)b[0], (bf16)b[1], (bf16)b[2], (bf16)b[3]};
  return r;
}

// --------------------------------------------------------------------
// Kernel 1: QKV projection.  C[8192,3072] = X[8192,1024] @ W[3072,1024]^T
// --------------------------------------------------------------------
__global__ __launch_bounds__(256) void k_qkv(const float* __restrict__ X,
                                             const float* __restrict__ W,
                                             bf16* __restrict__ Q,
                                             bf16* __restrict__ Kc,
                                             bf16* __restrict__ Vt) {
  constexpr int K = 1024;
  __shared__ __align__(16) bf16 As[128 * 64];
  __shared__ __align__(16) bf16 Bs[128 * 64];
  const int t = threadIdx.x;
  const int lane = t & 63, w = t >> 6;
  const int wr = w >> 1, wc = w & 1;
  const int li = lane & 15, g = lane >> 4;
  const int m0 = (blockIdx.x & 63) * 128;   // 64 m-tiles
  const int n0 = (blockIdx.x >> 6) * 128;   // 24 n-tiles

  f32x4 acc[4][4] = {};

  for (int kt = 0; kt < K; kt += 64) {
#pragma unroll
    for (int it = 0; it < 4; ++it) {
      int c = it * 256 + t;               // 0..1023, 8 bf16 elems each
      int row = c >> 3, col = (c & 7) << 3;
      *(bf16x8*)(As + c * 8) = cvt8(X + (size_t)(m0 + row) * K + kt + col);
      *(bf16x8*)(Bs + c * 8) = cvt8(W + (size_t)(n0 + row) * K + kt + col);
    }
    __syncthreads();
#pragma unroll
    for (int kk = 0; kk < 2; ++kk) {
      bf16x8 af[4], bfr[4];
#pragma unroll
      for (int i = 0; i < 4; ++i)
        af[i] = *(const bf16x8*)(As + (wr * 64 + i * 16 + li) * 64 + kk * 32 + g * 8);
#pragma unroll
      for (int j = 0; j < 4; ++j)
        bfr[j] = *(const bf16x8*)(Bs + (wc * 64 + j * 16 + li) * 64 + kk * 32 + g * 8);
#pragma unroll
      for (int i = 0; i < 4; ++i)
#pragma unroll
        for (int j = 0; j < 4; ++j)
          acc[i][j] = MFMA_BF16(af[i], bfr[j], acc[i][j]);
    }
    __syncthreads();
  }

#pragma unroll
  for (int i = 0; i < 4; ++i) {
#pragma unroll
    for (int j = 0; j < 4; ++j) {
      int col = n0 + wc * 64 + j * 16 + li;
      int h = col / 192, r = col % 192;
#pragma unroll
      for (int rg = 0; rg < 4; ++rg) {
        int row = m0 + wr * 64 + i * 16 + g * 4 + rg;
        int b = row >> 10, l = row & 1023;
        bf16 v = (bf16)acc[i][j][rg];
        if (r < 64)
          Q[((size_t)((b * 16 + h) * 1024 + l)) * 64 + r] = v;
        else if (r < 128)
          Kc[((size_t)((b * 16 + h) * 1024 + l)) * 64 + (r - 64)] = v;
        else
          Vt[((size_t)((b * 16 + h) * 64 + (r - 128))) * 1024 + l] = v;
      }
    }
  }
}

// --------------------------------------------------------------------
// Kernel 2: flash attention. Grid 2048 x 256 threads; bh = lid%128 so all
// 16 q-tiles of one head land on the same XCD. Per wave: 16 q rows.
// Swapped QK^T: s[kkf][rg] = S[q=q0+li][k = kkt + kkf*16 + g*4 + rg].
// bias/mask prefetched one k-tile ahead; mask folded into bias (c4) early.
// P goes through per-wave parity-double-buffered LDS slice; all DS
// ordering left to the compiler (no barriers, no sched walls).
// --------------------------------------------------------------------
__global__ __launch_bounds__(256) void k_attn(const bf16* __restrict__ Q,
                                              const bf16* __restrict__ Kc,
                                              const bf16* __restrict__ Vt,
                                              const float* __restrict__ bias,
                                              const int* __restrict__ mask,
                                              bf16* __restrict__ Vals) {
  __shared__ __align__(16) bf16 Plds[4][2][16][72];  // per-wave, pad-72 rows
  const int t = threadIdx.x, lane = t & 63, w = t >> 6;
  const int li = lane & 15, g = lane >> 4;
  const int lid = blockIdx.x;
  const int bh = lid & 127;            // b*16+h; lid%8 == bh%8 -> same XCD
  const int qt = lid >> 7;
  const int b = bh >> 4, h = bh & 15;
  const int q0 = qt * 64 + w * 16;     // wave's 16 q rows

  const bf16* Qbase = Q + ((size_t)bh << 10) * 64;
  const bf16* Kbase = Kc + ((size_t)bh << 10) * 64;
  const bf16* Vbase = Vt + ((size_t)bh << 6) * 1024;
  const float* brow = bias + ((size_t)bh << 20) + (size_t)(q0 + li) * 1024 + g * 4;
  const int*   mrow = mask + ((size_t)bh << 20) + (size_t)(q0 + li) * 1024 + g * 4;

  bf16x8 qf[2];
#pragma unroll
  for (int c = 0; c < 2; ++c)
    qf[c] = *(const bf16x8*)(Qbase + (size_t)(q0 + li) * 64 + c * 32 + g * 8);

  f32x4 oacc[4] = {};
  float mrun = NEGF;
  float lrun = 0.f;

  // ---- prologue: issue tile-0 bias/mask loads ----
  f32x4 b4[4];
  i32x4 m4[4];
#pragma unroll
  for (int kkf = 0; kkf < 4; ++kkf) {
    b4[kkf] = *(const f32x4*)(brow + kkf * 16);
    m4[kkf] = *(const i32x4*)(mrow + kkf * 16);
  }

  for (int kt6 = 0; kt6 < 16; ++kt6) {
    const int kkt = kt6 * 64;
    const int par = kt6 & 1;

    // ---- consume prefetched bias/mask: fold mask into bias ----
    f32x4 c4[4];
#pragma unroll
    for (int kkf = 0; kkf < 4; ++kkf)
#pragma unroll
      for (int rg = 0; rg < 4; ++rg)
        c4[kkf][rg] = m4[kkf][rg] ? NEGF : b4[kkf][rg];

    // ---- issue next tile's bias/mask loads (hidden under QK+softmax+PV) ----
    if (kt6 < 15) {
#pragma unroll
      for (int kkf = 0; kkf < 4; ++kkf) {
        b4[kkf] = *(const f32x4*)(brow + kkt + 64 + kkf * 16);
        m4[kkf] = *(const i32x4*)(mrow + kkt + 64 + kkf * 16);
      }
    }

    // ---- S^T = K Q^T (per wave: 64k x 16q as 4 fragments) ----
    f32x4 s[4];
#pragma unroll
    for (int kkf = 0; kkf < 4; ++kkf) {
      f32x4 ss = {0.f, 0.f, 0.f, 0.f};
#pragma unroll
      for (int c = 0; c < 2; ++c) {
        bf16x8 kf = *(const bf16x8*)(Kbase + (size_t)(kkt + kkf * 16 + li) * 64 + c * 32 + g * 8);
        ss = MFMA_BF16(kf, qf[c], ss);
      }
      s[kkf] = ss;
    }

    // ---- scale + masked-bias, tile max ----
    float tmax = NEGF;
#pragma unroll
    for (int kkf = 0; kkf < 4; ++kkf) {
#pragma unroll
      for (int rg = 0; rg < 4; ++rg) {
        float sv = __builtin_fmaf(s[kkf][rg], SCALE_, c4[kkf][rg]);
        s[kkf][rg] = sv;
        tmax = fmaxf(tmax, sv);
      }
    }
    tmax = fmaxf(tmax, __shfl_xor(tmax, 16));
    tmax = fmaxf(tmax, __shfl_xor(tmax, 32));

    float mnew = fmaxf(mrun, tmax);
    float corr = __expf(mrun - mnew);   // NEG-NEG=0 -> 1; NEG-real -> 0
    float psum = 0.f;

    // ---- P = exp(s - m): pack pairs, b32 LDS writes (pad-72 spreads banks) ----
#pragma unroll
    for (int kkf = 0; kkf < 4; ++kkf) {
      float p0 = __expf(s[kkf][0] - mnew);
      float p1 = __expf(s[kkf][1] - mnew);
      float p2 = __expf(s[kkf][2] - mnew);
      float p3 = __expf(s[kkf][3] - mnew);
      psum += (p0 + p1) + (p2 + p3);
      bf16x2 pa = {(bf16)p0, (bf16)p1};
      bf16x2 pb = {(bf16)p2, (bf16)p3};
      *(bf16x2*)(&Plds[w][par][li][kkf * 16 + g * 4])     = pa;
      *(bf16x2*)(&Plds[w][par][li][kkf * 16 + g * 4 + 2]) = pb;
    }
    psum += __shfl_xor(psum, 16);
    psum += __shfl_xor(psum, 32);
    lrun = lrun * corr + psum;
    mrun = mnew;

    // ---- rescale O by corr of the row each accumulator reg belongs to ----
    float cq[4];
#pragma unroll
    for (int rg = 0; rg < 4; ++rg) cq[rg] = __shfl(corr, g * 4 + rg);
#pragma unroll
    for (int af = 0; af < 4; ++af)
#pragma unroll
      for (int rg = 0; rg < 4; ++rg) oacc[af][rg] *= cq[rg];

    // ---- O += P V (compiler inserts the minimal lgkmcnt; V loads hoistable) ----
#pragma unroll
    for (int c = 0; c < 2; ++c) {
      bf16x8 pf = *(const bf16x8*)(&Plds[w][par][li][c * 32 + g * 8]);
#pragma unroll
      for (int af = 0; af < 4; ++af) {
        bf16x8 vf = *(const bf16x8*)(Vbase + (size_t)(af * 16 + li) * 1024 + kkt + c * 32 + g * 8);
        oacc[af] = MFMA_BF16(pf, vf, oacc[af]);
      }
    }
  }

  float linv[4];
#pragma unroll
  for (int rg = 0; rg < 4; ++rg) linv[rg] = 1.0f / __shfl(lrun, g * 4 + rg);
#pragma unroll
  for (int af = 0; af < 4; ++af) {
#pragma unroll
    for (int rg = 0; rg < 4; ++rg) {
      int q = q0 + g * 4 + rg;
      int col = h * 64 + af * 16 + li;
      Vals[(((size_t)(b * 1024 + q)) << 10) + col] = (bf16)(oacc[af][rg] * linv[rg]);
    }
  }
}

// --------------------------------------------------------------------
// Kernel 3: output projection. out[8192,1024] = Vals @ Wout[1024,1024]^T
// --------------------------------------------------------------------
__global__ __launch_bounds__(256) void k_out(const bf16* __restrict__ X,
                                             const float* __restrict__ W,
                                             float* __restrict__ Out) {
  constexpr int K = 1024;
  __shared__ __align__(16) bf16 As[128 * 64];
  __shared__ __align__(16) bf16 Bs[128 * 64];
  const int t = threadIdx.x;
  const int lane = t & 63, w = t >> 6;
  const int wr = w >> 1, wc = w & 1;
  const int li = lane & 15, g = lane >> 4;
  const int m0 = (blockIdx.x & 63) * 128;   // 64 m-tiles
  const int n0 = (blockIdx.x >> 6) * 128;   // 8 n-tiles

  f32x4 acc[4][4] = {};

  for (int kt = 0; kt < K; kt += 64) {
#pragma unroll
    for (int it = 0; it < 4; ++it) {
      int c = it * 256 + t;
      int row = c >> 3, col = (c & 7) << 3;
      gload_lds16(X + (size_t)(m0 + row) * K + kt + col, As + c * 8);
      *(bf16x8*)(Bs + c * 8) = cvt8(W + (size_t)(n0 + row) * K + kt + col);
    }
    __syncthreads();
#pragma unroll
    for (int kk = 0; kk < 2; ++kk) {
      bf16x8 af[4], bfr[4];
#pragma unroll
      for (int i = 0; i < 4; ++i)
        af[i] = *(const bf16x8*)(As + (wr * 64 + i * 16 + li) * 64 + kk * 32 + g * 8);
#pragma unroll
      for (int j = 0; j < 4; ++j)
        bfr[j] = *(const bf16x8*)(Bs + (wc * 64 + j * 16 + li) * 64 + kk * 32 + g * 8);
#pragma unroll
      for (int i = 0; i < 4; ++i)
#pragma unroll
        for (int j = 0; j < 4; ++j)
          acc[i][j] = MFMA_BF16(af[i], bfr[j], acc[i][j]);
    }
    __syncthreads();
  }

#pragma unroll
  for (int i = 0; i < 4; ++i) {
#pragma unroll
    for (int j = 0; j < 4; ++j) {
      int col = n0 + wc * 64 + j * 16 + li;
#pragma unroll
      for (int rg = 0; rg < 4; ++rg) {
        int row = m0 + wr * 64 + i * 16 + g * 4 + rg;
        Out[((size_t)row << 10) + col] = acc[i][j][rg];
      }
    }
  }
}

// --------------------------------------------------------------------
extern "C" void kernel_launch(void* const* d_in, const int* in_sizes, int n_in,
                              void* d_out, int out_size, void* d_ws, size_t ws_size,
                              hipStream_t stream) {
  const float* emb  = (const float*)d_in[0];
  const int*   mask = (const int*)d_in[1];
  const float* bias = (const float*)d_in[2];
  const float* Wqkv = (const float*)d_in[3];
  const float* Wout = (const float*)d_in[4];
  float* out = (float*)d_out;

  const size_t HEADS_ELEMS = (size_t)8 * 16 * 1024 * 64;  // 8.39M elems
  bf16* Q    = (bf16*)d_ws;
  bf16* Kc   = Q + HEADS_ELEMS;
  bf16* Vt   = Kc + HEADS_ELEMS;
  bf16* Vals = Vt + HEADS_ELEMS;   // total ~67 MiB of ws

  k_qkv<<<dim3(64 * 24), 256, 0, stream>>>(emb, Wqkv, Q, Kc, Vt);
  k_attn<<<dim3(2048), 256, 0, stream>>>(Q, Kc, Vt, bias, mask, Vals);
  k_out<<<dim3(64 * 8), 256, 0, stream>>>(Vals, Wout, out);
}